// Round 8
// baseline (96.142 us; speedup 1.0000x reference)
//
#include <hip/hip_runtime.h>
#include <math.h>

// OuterLaplaceAggregation: complex first-order linear scan.
//   s_t = lambda * s_{t-1} + x_t,  s_{-1} = memory,  out = Re(s) [b,t,f,c]
//   lambda_{f,c} = exp(clip(a[f],-LIMIT,-1e-8) + i*b[c])
// B=8 T=512 F=1024 C=4.
//
// SINGLE kernel, LDS chunked scan. Block = (b, 16-feature group), 1024
// threads = 16 f x 64 chunks (LL=8 steps each). Phase A: chunk scan with
// x in registers -> 32B aggregate to LDS. Phase B: fold memory seed +
// predecessor aggregates (lambda^8 via 3 complex squarings). Phase C:
// replay, nontemporal float4 stores. 512 blocks x 16 waves = 32 waves/CU
// (max occupancy); low-j waves start storing early while high-j waves
// still fold -> store stream flows for most of the kernel (vs NCH=32
// round: stores bunched into a synchronized tail at 16 waves/CU).

#define BB 8
#define TT 512
#define FF 1024
#define CC 4
#define NCH 64
#define LL (TT / NCH)          // 8
#define FG 16                  // features per block
#define LIMIT_F 0.07664339751178941f

typedef float v4f __attribute__((ext_vector_type(4)));

__global__ __launch_bounds__(1024) void
scan_lds_kernel(const float* __restrict__ x,
                const float* __restrict__ mem_r,
                const float* __restrict__ mem_i,
                const float* __restrict__ a_vec,
                const float* __restrict__ b_vec,
                float* __restrict__ out,
                long long x_lim, long long mem_lim,
                long long out4_lim, long long imag_off4)
{
    const int tid = threadIdx.x;           // [0,1024)
    const int bid = blockIdx.x;            // [0,512)
    const int fg  = bid & 63;              // feature group
    const int b   = bid >> 6;              // batch
    const int fl  = tid & (FG - 1);        // 0..15
    const int j   = tid >> 4;              // chunk 0..63
    const int f   = fg * FG + fl;

    // lambda per c
    const float af = fminf(fmaxf(a_vec[f], -LIMIT_F), -1e-8f);
    const float ea = expf(af);
    float lr[CC], li[CC];
#pragma unroll
    for (int c = 0; c < CC; ++c) {
        float s, cz;
        sincosf(b_vec[c], &s, &cz);
        lr[c] = ea * cz;
        li[c] = ea * s;
    }

    // ---- load this chunk's x into registers ----
    const long long xbase = ((long long)b * TT + j * LL) * FF + f;
    const bool xok = (xbase + (long long)(LL - 1) * FF) < x_lim;
    float xv[LL];
#pragma unroll
    for (int t = 0; t < LL; ++t)
        xv[t] = xok ? x[xbase + (long long)t * FF] : 0.f;

    // ---- phase A: chunk-local scan, zero seed ----
    float er[CC] = {0.f, 0.f, 0.f, 0.f}, ei[CC] = {0.f, 0.f, 0.f, 0.f};
#pragma unroll
    for (int t = 0; t < LL; ++t) {
#pragma unroll
        for (int c = 0; c < CC; ++c) {
            const float nr = fmaf(lr[c], er[c], fmaf(-li[c], ei[c], xv[t]));
            const float ni = fmaf(li[c], er[c], lr[c] * ei[c]);
            er[c] = nr; ei[c] = ni;
        }
    }

    // aggregate exchange via LDS: agg[j][fl] = 4x (re,im) = 32 B
    __shared__ float agg[NCH][FG][8];      // 32 KB
    {
        v4f* w4 = (v4f*)&agg[j][fl][0];
        w4[0] = (v4f){er[0], ei[0], er[1], ei[1]};
        w4[1] = (v4f){er[2], ei[2], er[3], ei[3]};
    }
    __syncthreads();

    // ---- phase B: lambda^LL via 3 complex squarings; fold predecessors ----
    float lLr[CC], lLi[CC];
#pragma unroll
    for (int c = 0; c < CC; ++c) {
        float pr = lr[c], pi = li[c];
#pragma unroll
        for (int k = 0; k < 3; ++k) {      // ^2 three times -> ^8
            const float nr = fmaf(pr, pr, -(pi * pi));
            const float ni = 2.f * pr * pi;
            pr = nr; pi = ni;
        }
        lLr[c] = pr; lLi[c] = pi;
    }

    float sr[CC], si[CC];
#pragma unroll
    for (int c = 0; c < CC; ++c) {
        const long long m = (long long)(b * FF + f) * CC + c;
        sr[c] = (m < mem_lim) ? mem_r[m] : 0.f;
        si[c] = (m < mem_lim) ? mem_i[m] : 0.f;
    }

    for (int i = 0; i < j; ++i) {          // <=63 folds, LDS reads
        const v4f* r4 = (const v4f*)&agg[i][fl][0];
        const v4f A = r4[0], Bv = r4[1];
        const float ar[CC] = {A.x, A.z, Bv.x, Bv.z};
        const float ai[CC] = {A.y, A.w, Bv.y, Bv.w};
#pragma unroll
        for (int c = 0; c < CC; ++c) {
            const float nr = fmaf(lLr[c], sr[c], fmaf(-lLi[c], si[c], ar[c]));
            const float ni = fmaf(lLi[c], sr[c], fmaf(lLr[c], si[c], ai[c]));
            sr[c] = nr; si[c] = ni;
        }
    }

    // ---- phase C: replay from registers, NT-store ----
    v4f* out4 = (v4f*)out;
    const long long obase = xbase;         // float4 index: (b*T+t)*F + f
    const bool rok = (obase + (long long)(LL - 1) * FF) < out4_lim;
    const bool iok = (imag_off4 > 0) &&
                     ((obase + imag_off4 + (long long)(LL - 1) * FF) < out4_lim);

#pragma unroll
    for (int t = 0; t < LL; ++t) {
#pragma unroll
        for (int c = 0; c < CC; ++c) {
            const float nr = fmaf(lr[c], sr[c], fmaf(-li[c], si[c], xv[t]));
            const float ni = fmaf(li[c], sr[c], lr[c] * si[c]);
            sr[c] = nr; si[c] = ni;
        }
        if (rok) __builtin_nontemporal_store(
            (v4f){sr[0], sr[1], sr[2], sr[3]},
            &out4[obase + (long long)t * FF]);
        if (iok) __builtin_nontemporal_store(
            (v4f){si[0], si[1], si[2], si[3]},
            &out4[obase + imag_off4 + (long long)t * FF]);
    }
}

extern "C" void kernel_launch(void* const* d_in, const int* in_sizes, int n_in,
                              void* d_out, int out_size, void* d_ws, size_t ws_size,
                              hipStream_t stream)
{
    const float* x     = (const float*)d_in[0];
    const float* mem_r = (const float*)d_in[1];
    const float* mem_i = (const float*)d_in[2];
    const float* a_vec = (const float*)d_in[3];
    const float* b_vec = (const float*)d_in[4];
    float* out = (float*)d_out;

    const long long x_lim   = (long long)in_sizes[0];       // 4,194,304
    const long long mem_lim = (long long)in_sizes[1];       // 32,768
    const long long BTFC = (long long)BB * TT * FF * CC;    // 16,777,216
    const long long out4_lim = (long long)out_size / 4;
    const long long imag_off4 = ((long long)out_size >= 2 * BTFC) ? (BTFC / 4) : 0;

    const int grid = BB * (FF / FG);       // 512 blocks
    scan_lds_kernel<<<grid, 1024, 0, stream>>>(
        x, mem_r, mem_i, a_vec, b_vec, out,
        x_lim, mem_lim, out4_lim, imag_off4);
}

// Round 9
// 93.659 us; speedup vs baseline: 1.0265x; 1.0265x over previous
//
#include <hip/hip_runtime.h>
#include <math.h>

// OuterLaplaceAggregation: complex first-order linear scan.
//   s_t = lambda * s_{t-1} + x_t,  s_{-1} = memory,  out = Re(s) [b,t,f,c]
//   lambda_{f,c} = exp(clip(a[f],-LIMIT,-1e-8) + i*b[c])
// B=8 T=512 F=1024 C=4.
//
// SINGLE kernel, LDS-based chunked scan. Block = (b, 16-feature group),
// 512 threads = 16 f x 32 chunks (LL=16 steps each). Phase A: local chunk
// scan with x in registers -> aggregate to LDS. Phase B: fold memory seed
// + predecessor aggregates (lambda^16 via 4 complex squarings). Phase C:
// replay from registers, REGULAR float4 stores (A/B vs round 7's
// nontemporal: NT was introduced untested alongside structural changes;
// m13's 6.3 TB/s ceiling was measured with regular stores).

#define BB 8
#define TT 512
#define FF 1024
#define CC 4
#define NCH 32
#define LL (TT / NCH)          // 16
#define FG 16                  // features per block
#define LIMIT_F 0.07664339751178941f

typedef float v4f __attribute__((ext_vector_type(4)));

__global__ __launch_bounds__(512) void
scan_lds_kernel(const float* __restrict__ x,
                const float* __restrict__ mem_r,
                const float* __restrict__ mem_i,
                const float* __restrict__ a_vec,
                const float* __restrict__ b_vec,
                float* __restrict__ out,
                long long x_lim, long long mem_lim,
                long long out4_lim, long long imag_off4)
{
    const int tid = threadIdx.x;           // [0,512)
    const int bid = blockIdx.x;            // [0,512)
    const int fg  = bid & 63;              // feature group
    const int b   = bid >> 6;              // batch
    const int fl  = tid & (FG - 1);        // 0..15
    const int j   = tid >> 4;              // chunk 0..31
    const int f   = fg * FG + fl;

    // lambda per c
    const float af = fminf(fmaxf(a_vec[f], -LIMIT_F), -1e-8f);
    const float ea = expf(af);
    float lr[CC], li[CC];
#pragma unroll
    for (int c = 0; c < CC; ++c) {
        float s, cz;
        sincosf(b_vec[c], &s, &cz);
        lr[c] = ea * cz;
        li[c] = ea * s;
    }

    // ---- load this chunk's x into registers ----
    const long long xbase = ((long long)b * TT + j * LL) * FF + f;
    const bool xok = (xbase + (long long)(LL - 1) * FF) < x_lim;
    float xv[LL];
#pragma unroll
    for (int t = 0; t < LL; ++t)
        xv[t] = xok ? x[xbase + (long long)t * FF] : 0.f;

    // ---- phase A: chunk-local scan, zero seed ----
    float er[CC] = {0.f, 0.f, 0.f, 0.f}, ei[CC] = {0.f, 0.f, 0.f, 0.f};
#pragma unroll
    for (int t = 0; t < LL; ++t) {
#pragma unroll
        for (int c = 0; c < CC; ++c) {
            const float nr = fmaf(lr[c], er[c], fmaf(-li[c], ei[c], xv[t]));
            const float ni = fmaf(li[c], er[c], lr[c] * ei[c]);
            er[c] = nr; ei[c] = ni;
        }
    }

    // aggregate exchange via LDS: agg[j][fl] = 4x (re,im)
    __shared__ float agg[NCH][FG][8];
    {
        v4f* w4 = (v4f*)&agg[j][fl][0];
        w4[0] = (v4f){er[0], ei[0], er[1], ei[1]};
        w4[1] = (v4f){er[2], ei[2], er[3], ei[3]};
    }
    __syncthreads();

    // ---- phase B: lambda^LL via 4 complex squarings; fold predecessors ----
    float lLr[CC], lLi[CC];
#pragma unroll
    for (int c = 0; c < CC; ++c) {
        float pr = lr[c], pi = li[c];
#pragma unroll
        for (int k = 0; k < 4; ++k) {      // ^2 four times -> ^16
            const float nr = fmaf(pr, pr, -(pi * pi));
            const float ni = 2.f * pr * pi;
            pr = nr; pi = ni;
        }
        lLr[c] = pr; lLi[c] = pi;
    }

    float sr[CC], si[CC];
#pragma unroll
    for (int c = 0; c < CC; ++c) {
        const long long m = (long long)(b * FF + f) * CC + c;
        sr[c] = (m < mem_lim) ? mem_r[m] : 0.f;
        si[c] = (m < mem_lim) ? mem_i[m] : 0.f;
    }

    for (int i = 0; i < j; ++i) {          // <=31 folds, LDS reads
        const v4f* r4 = (const v4f*)&agg[i][fl][0];
        const v4f A = r4[0], Bv = r4[1];
        const float ar[CC] = {A.x, A.z, Bv.x, Bv.z};
        const float ai[CC] = {A.y, A.w, Bv.y, Bv.w};
#pragma unroll
        for (int c = 0; c < CC; ++c) {
            const float nr = fmaf(lLr[c], sr[c], fmaf(-lLi[c], si[c], ar[c]));
            const float ni = fmaf(lLi[c], sr[c], fmaf(lLr[c], si[c], ai[c]));
            sr[c] = nr; si[c] = ni;
        }
    }

    // ---- phase C: replay from registers, regular float4 stores ----
    v4f* out4 = (v4f*)out;
    const long long obase = xbase;         // float4 index: (b*T+t)*F + f
    const bool rok = (obase + (long long)(LL - 1) * FF) < out4_lim;
    const bool iok = (imag_off4 > 0) &&
                     ((obase + imag_off4 + (long long)(LL - 1) * FF) < out4_lim);

#pragma unroll
    for (int t = 0; t < LL; ++t) {
#pragma unroll
        for (int c = 0; c < CC; ++c) {
            const float nr = fmaf(lr[c], sr[c], fmaf(-li[c], si[c], xv[t]));
            const float ni = fmaf(li[c], sr[c], lr[c] * si[c]);
            sr[c] = nr; si[c] = ni;
        }
        if (rok) out4[obase + (long long)t * FF] =
            (v4f){sr[0], sr[1], sr[2], sr[3]};
        if (iok) out4[obase + imag_off4 + (long long)t * FF] =
            (v4f){si[0], si[1], si[2], si[3]};
    }
}

extern "C" void kernel_launch(void* const* d_in, const int* in_sizes, int n_in,
                              void* d_out, int out_size, void* d_ws, size_t ws_size,
                              hipStream_t stream)
{
    const float* x     = (const float*)d_in[0];
    const float* mem_r = (const float*)d_in[1];
    const float* mem_i = (const float*)d_in[2];
    const float* a_vec = (const float*)d_in[3];
    const float* b_vec = (const float*)d_in[4];
    float* out = (float*)d_out;

    const long long x_lim   = (long long)in_sizes[0];       // 4,194,304
    const long long mem_lim = (long long)in_sizes[1];       // 32,768
    const long long BTFC = (long long)BB * TT * FF * CC;    // 16,777,216
    const long long out4_lim = (long long)out_size / 4;
    const long long imag_off4 = ((long long)out_size >= 2 * BTFC) ? (BTFC / 4) : 0;

    const int grid = BB * (FF / FG);       // 512 blocks
    scan_lds_kernel<<<grid, 512, 0, stream>>>(
        x, mem_r, mem_i, a_vec, b_vec, out,
        x_lim, mem_lim, out4_lim, imag_off4);
}